// Round 1
// baseline (1205.533 us; speedup 1.0000x reference)
//
#include <hip/hip_runtime.h>
#include <stdint.h>
#include <math.h>

typedef __attribute__((ext_vector_type(8))) short short8;
typedef __attribute__((ext_vector_type(4))) float f32x4;

typedef const __attribute__((address_space(1))) void* gas_ptr;
typedef __attribute__((address_space(3))) void* las_ptr;

__device__ __forceinline__ void gld_lds16(const void* g, void* l) {
    // async global->LDS, 16B per lane, LDS dest = wave-uniform base + lane*16
    __builtin_amdgcn_global_load_lds((gas_ptr)g, (las_ptr)l, 16, 0, 0);
}

__device__ __forceinline__ unsigned short f32_to_bf16_rne(float f) {
    unsigned u = __builtin_bit_cast(unsigned, f);
    u += 0x7FFFu + ((u >> 16) & 1u);
    return (unsigned short)(u >> 16);
}

// ---------------- stats: pass 1 (per-block partial sum/sumsq in double) ----------------
__global__ void stats_partial_kernel(const float* __restrict__ w, int n4, double* __restrict__ partials) {
    __shared__ double ssum[256];
    __shared__ double ssq[256];
    int t = threadIdx.x;
    long i = (long)blockIdx.x * blockDim.x + t;
    long stride = (long)gridDim.x * blockDim.x;
    double s = 0.0, q = 0.0;
    for (; i < n4; i += stride) {
        float4 v = ((const float4*)w)[i];
        s += (double)v.x + (double)v.y + (double)v.z + (double)v.w;
        q += (double)v.x * v.x + (double)v.y * v.y + (double)v.z * v.z + (double)v.w * v.w;
    }
    ssum[t] = s; ssq[t] = q;
    __syncthreads();
    for (int off = 128; off > 0; off >>= 1) {
        if (t < off) { ssum[t] += ssum[t + off]; ssq[t] += ssq[t + off]; }
        __syncthreads();
    }
    if (t == 0) {
        partials[2 * blockIdx.x]     = ssum[0];
        partials[2 * blockIdx.x + 1] = ssq[0];
    }
}

// ---------------- stats: pass 2 (finalize -> lower/upper bounds as float) ----------------
__global__ void stats_final_kernel(const double* __restrict__ partials, int nblocks, long n,
                                   float* __restrict__ bounds) {
    __shared__ double ssum[256];
    __shared__ double ssq[256];
    int t = threadIdx.x;
    double s = 0.0, q = 0.0;
    for (int i = t; i < nblocks; i += 256) {
        s += partials[2 * i];
        q += partials[2 * i + 1];
    }
    ssum[t] = s; ssq[t] = q;
    __syncthreads();
    for (int off = 128; off > 0; off >>= 1) {
        if (t < off) { ssum[t] += ssum[t + off]; ssq[t] += ssq[t + off]; }
        __syncthreads();
    }
    if (t == 0) {
        double sum = ssum[0], sumsq = ssq[0];
        double mean = sum / (double)n;
        double var = (sumsq - sum * sum / (double)n) / (double)(n - 1); // ddof=1
        double sd = sqrt(var);
        bounds[0] = (float)(mean - sd);
        bounds[1] = (float)(mean + sd);
    }
}

// ---------------- binarize weight -> bf16 bits ----------------
__global__ void binarize_w_kernel(const float* __restrict__ w, const float* __restrict__ bounds,
                                  unsigned short* __restrict__ wb, long n4) {
    float lo = bounds[0], hi = bounds[1];
    long i = (long)blockIdx.x * blockDim.x + threadIdx.x;
    if (i >= n4) return;
    float4 v = ((const float4*)w)[i];
    float r[4] = {v.x, v.y, v.z, v.w};
    ushort4 o;
    unsigned short ob[4];
#pragma unroll
    for (int j = 0; j < 4; j++) {
        float f = r[j];
        bool outlier = (f < lo) || (f > hi);
        float b = outlier ? f : (f > 0.f ? 1.f : (f < 0.f ? -1.f : 0.f));
        ob[j] = f32_to_bf16_rne(b);
    }
    o.x = ob[0]; o.y = ob[1]; o.z = ob[2]; o.w = ob[3];
    ((ushort4*)wb)[i] = o;
}

// ---------------- convert x -> bf16 bits ----------------
__global__ void convert_x_kernel(const float* __restrict__ x, unsigned short* __restrict__ xb, long n4) {
    long i = (long)blockIdx.x * blockDim.x + threadIdx.x;
    if (i >= n4) return;
    float4 v = ((const float4*)x)[i];
    ushort4 o;
    o.x = f32_to_bf16_rne(v.x);
    o.y = f32_to_bf16_rne(v.y);
    o.z = f32_to_bf16_rne(v.z);
    o.w = f32_to_bf16_rne(v.w);
    ((ushort4*)xb)[i] = o;
}

// ---------------- bf16 MFMA GEMM: C[M,N] = A[M,K] * B[N,K]^T + bias ----------------
// 128x128 tile, BK=64, 256 threads = 4 waves in 2x2, each wave 64x64 via 4x4 MFMA 16x16x32.
#define BM 128
#define BN 128
#define BK 64

__global__ __launch_bounds__(256) void gemm_bt_kernel(
    const unsigned short* __restrict__ A,   // [M,K] bf16 bits
    const unsigned short* __restrict__ B,   // [N,K] bf16 bits
    const float* __restrict__ bias,         // [N]
    float* __restrict__ C,                  // [M,N] fp32
    int M, int N, int K)
{
    __shared__ __align__(16) unsigned short As[BM * BK]; // 16 KB, chunk-swizzled
    __shared__ __align__(16) unsigned short Bs[BN * BK]; // 16 KB

    const int t = threadIdx.x;
    const int wave = t >> 6;
    const int lane = t & 63;
    const int wr = wave >> 1;      // wave row (0..1) -> 64 rows
    const int wc = wave & 1;       // wave col (0..1) -> 64 cols
    const int lm = lane & 15;
    const int quad = lane >> 4;
    const int sw = lm & 7;         // XOR swizzle key for fragment reads

    const int tile_m = blockIdx.y * BM;
    const int tile_n = blockIdx.x * BN;

    f32x4 acc[4][4] = {};

    // staging geometry: 1024 16B-chunks per tile; chunk c: row=c>>3, kc=c&7, swizzled src kc^(row&7)
    int row_[4], src_[4];
#pragma unroll
    for (int j = 0; j < 4; j++) {
        int c = j * 256 + t;
        int r = c >> 3, kc = c & 7;
        row_[j] = r;
        src_[j] = (kc ^ (r & 7)) * 8; // element offset within the BK=64 span
    }
    const int lds_base = wave * 512; // elements; + j*2048 per call

    const size_t Astripe = (size_t)tile_m * K;
    const size_t Bstripe = (size_t)tile_n * K;

    for (int kt = 0; kt < K; kt += BK) {
#pragma unroll
        for (int j = 0; j < 4; j++) {
            gld_lds16(A + Astripe + (size_t)row_[j] * K + kt + src_[j], &As[j * 2048 + lds_base]);
            gld_lds16(B + Bstripe + (size_t)row_[j] * K + kt + src_[j], &Bs[j * 2048 + lds_base]);
        }
        __syncthreads();

#pragma unroll
        for (int s = 0; s < 2; s++) {
            short8 af[4], bf[4];
#pragma unroll
            for (int i = 0; i < 4; i++) {
                int arow = wr * 64 + i * 16 + lm;
                int achunk = (s * 4 + quad) ^ sw;
                af[i] = *(const short8*)&As[arow * 64 + achunk * 8];
                int brow = wc * 64 + i * 16 + lm;
                bf[i] = *(const short8*)&Bs[brow * 64 + achunk * 8];
            }
#pragma unroll
            for (int i = 0; i < 4; i++)
#pragma unroll
                for (int j = 0; j < 4; j++)
                    acc[i][j] = __builtin_amdgcn_mfma_f32_16x16x32_bf16(af[i], bf[j], acc[i][j], 0, 0, 0);
        }
        __syncthreads();
    }

    // epilogue: C[row=(quad*4+r)][col=lm] per 16x16 tile, + bias
#pragma unroll
    for (int j = 0; j < 4; j++) {
        int col = tile_n + wc * 64 + j * 16 + lm;
        float bv = bias[col];
#pragma unroll
        for (int i = 0; i < 4; i++) {
            int row0 = tile_m + wr * 64 + i * 16 + quad * 4;
#pragma unroll
            for (int r = 0; r < 4; r++) {
                C[(size_t)(row0 + r) * N + col] = acc[i][j][r] + bv;
            }
        }
    }
}

// ---------------- fallback: fp32 tiled GEMM with on-the-fly binarize (correctness net) ----------------
__global__ void gemm_fallback_kernel(const float* __restrict__ A, const float* __restrict__ W,
                                     const float* __restrict__ bias, const float* __restrict__ bounds,
                                     float* __restrict__ C, int M, int N, int K) {
    __shared__ float as[16][16];
    __shared__ float wsm[16][17];
    int tx = threadIdx.x, ty = threadIdx.y;
    int row = blockIdx.y * 16 + ty;
    int col = blockIdx.x * 16 + tx;
    float lo = bounds[0], hi = bounds[1];
    float acc = 0.f;
    for (int k0 = 0; k0 < K; k0 += 16) {
        as[ty][tx] = A[(size_t)row * K + k0 + tx];
        float wv = W[(size_t)(blockIdx.x * 16 + ty) * K + k0 + tx];
        bool outlier = (wv < lo) || (wv > hi);
        wsm[ty][tx] = outlier ? wv : (wv > 0.f ? 1.f : (wv < 0.f ? -1.f : 0.f));
        __syncthreads();
#pragma unroll
        for (int k = 0; k < 16; k++) acc += as[ty][k] * wsm[tx][k];
        __syncthreads();
    }
    C[(size_t)row * N + col] = acc + bias[col];
}

extern "C" void kernel_launch(void* const* d_in, const int* in_sizes, int n_in,
                              void* d_out, int out_size, void* d_ws, size_t ws_size,
                              hipStream_t stream) {
    const float* x    = (const float*)d_in[0];
    const float* w    = (const float*)d_in[1];
    const float* bias = (const float*)d_in[2];
    float* out = (float*)d_out;

    const int  N  = in_sizes[2];                 // 4096
    const long wn = (long)in_sizes[1];           // 16777216
    const int  K  = (int)(wn / N);               // 4096
    const long xn = (long)in_sizes[0];           // 67108864
    const int  M  = (int)(xn / K);               // 16384

    char* ws = (char*)d_ws;
    float*  bounds   = (float*)ws;                       // 8 B
    double* partials = (double*)(ws + 64);               // 1024 * 16 B = 16 KB
    const size_t wb_off = 16512;                         // 64+16384 rounded; 128B aligned
    unsigned short* wb = (unsigned short*)(ws + wb_off); // 32 MB
    const size_t xb_off = wb_off + (size_t)wn * 2;
    unsigned short* xb = (unsigned short*)(ws + xb_off); // 128 MB
    const size_t need_full = xb_off + (size_t)xn * 2;

    // stats (always)
    stats_partial_kernel<<<1024, 256, 0, stream>>>(w, (int)(wn / 4), partials);
    stats_final_kernel<<<1, 256, 0, stream>>>(partials, 1024, wn, bounds);

    if (ws_size >= need_full) {
        long wn4 = wn / 4, xn4 = xn / 4;
        binarize_w_kernel<<<(int)((wn4 + 255) / 256), 256, 0, stream>>>(w, bounds, wb, wn4);
        convert_x_kernel<<<(int)((xn4 + 255) / 256), 256, 0, stream>>>(x, xb, xn4);
        dim3 grid(N / BN, M / BM);
        gemm_bt_kernel<<<grid, 256, 0, stream>>>(xb, wb, bias, out, M, N, K);
    } else {
        dim3 grid(N / 16, M / 16), blk(16, 16);
        gemm_fallback_kernel<<<grid, blk, 0, stream>>>(x, w, bias, bounds, out, M, N, K);
    }
}